// Round 2
// baseline (149.608 us; speedup 1.0000x reference)
//
#include <hip/hip_runtime.h>

#define L_IN   32768
#define L_OUT  32766   // (32768 - 3)/1 + 1
#define C_IN   32
#define C_OUT  32
#define KW     3
#define TILE_L 256               // output positions per block
#define XROW   260               // TILE_L + 2 halo, padded to float4 multiple
#define NTILES 128               // 32768 / 256 (covers all 32766 outputs)

__global__ __launch_bounds__(256) void conv1d_kernel(
    const float* __restrict__ x, const float* __restrict__ w,
    float* __restrict__ out)
{
    __shared__ __attribute__((aligned(16))) float xs[C_IN * XROW];      // [ci][col]
    __shared__ __attribute__((aligned(16))) float ws[C_IN * C_OUT * KW]; // [ci][co][k]

    const int tid       = threadIdx.x;
    const int blk       = blockIdx.x;          // 0 .. 16*128-1
    const int b         = blk >> 7;            // / NTILES
    const int tile      = blk & (NTILES - 1);
    const int tile_base = tile << 8;           // * TILE_L

    // ---- stage x tile: xs[ci][0..257] = x[b][ci][tile_base .. tile_base+257]
    const float* xb = x + (size_t)b * C_IN * L_IN;
    for (int i = tid; i < C_IN * (XROW / 4); i += 256) {
        int ci  = i / (XROW / 4);
        int c4  = i - ci * (XROW / 4);
        int col = c4 * 4;
        int gl  = tile_base + col;
        const float* src = xb + (size_t)ci * L_IN;
        float4 v;
        if (gl + 3 < L_IN) {
            v = *(const float4*)(src + gl);
        } else {   // only last tile's tail lands here
            v.x = (gl + 0 < L_IN) ? src[gl + 0] : 0.f;
            v.y = (gl + 1 < L_IN) ? src[gl + 1] : 0.f;
            v.z = (gl + 2 < L_IN) ? src[gl + 2] : 0.f;
            v.w = (gl + 3 < L_IN) ? src[gl + 3] : 0.f;
        }
        *(float4*)&xs[ci * XROW + col] = v;
    }

    // ---- stage + transpose weights: ws[ci*96 + co*3 + k] = w[co*96 + ci*3 + k]
    // 3072 elements, 256 threads -> 12 iters, indices compile-time derivable
    for (int i = tid; i < C_IN * C_OUT * KW; i += 256) {
        int ci = i / (C_OUT * KW);       // /96
        int r  = i - ci * (C_OUT * KW);
        int co = r / KW;                 // /3
        int k  = r - co * KW;
        ws[i] = w[co * (C_IN * KW) + ci * KW + k];
    }
    __syncthreads();

    // ---- compute: wave-uniform co group (broadcast weight reads), 8co x 4L per thread
    const int lane = tid & 63;
    const int co0  = (tid >> 6) * 8;   // same for all 64 lanes of a wave
    const int l0   = lane * 4;         // local column of first output

    float acc[8][4];
    #pragma unroll
    for (int c = 0; c < 8; ++c)
        #pragma unroll
        for (int j = 0; j < 4; ++j) acc[c][j] = 0.f;

    const float* xp = &xs[l0];
    const float* wp = &ws[co0 * KW];

    #pragma unroll 2
    for (int ci = 0; ci < C_IN; ++ci) {
        float xv[6];
        float4 xa = *(const float4*)(xp);
        float2 xc = *(const float2*)(xp + 4);
        xv[0] = xa.x; xv[1] = xa.y; xv[2] = xa.z; xv[3] = xa.w;
        xv[4] = xc.x; xv[5] = xc.y;

        float wv[24];
        #pragma unroll
        for (int q = 0; q < 6; ++q) {
            float4 t = *(const float4*)(wp + q * 4);
            wv[q * 4 + 0] = t.x; wv[q * 4 + 1] = t.y;
            wv[q * 4 + 2] = t.z; wv[q * 4 + 3] = t.w;
        }

        #pragma unroll
        for (int c = 0; c < 8; ++c)
            #pragma unroll
            for (int j = 0; j < 4; ++j)
                #pragma unroll
                for (int k = 0; k < KW; ++k)
                    acc[c][j] = fmaf(wv[c * KW + k], xv[j + k], acc[c][j]);

        xp += XROW;
        wp += C_OUT * KW;
    }

    // ---- store (float2: out row stride 32766 breaks 16B alignment on odd rows)
    const int lg = tile_base + l0;                 // global output position
    float* ob = out + ((size_t)b * C_OUT + co0) * L_OUT + lg;
    #pragma unroll
    for (int c = 0; c < 8; ++c) {
        // lg <= 32764 and lg+1 <= 32765 always -> first pair always valid
        float2 v0; v0.x = acc[c][0]; v0.y = acc[c][1];
        *(float2*)(ob) = v0;
        if (lg + 3 < L_OUT) {
            float2 v1; v1.x = acc[c][2]; v1.y = acc[c][3];
            *(float2*)(ob + 2) = v1;
        } else {
            if (lg + 2 < L_OUT) ob[2] = acc[c][2];
        }
        ob += L_OUT;
    }
}

extern "C" void kernel_launch(void* const* d_in, const int* in_sizes, int n_in,
                              void* d_out, int out_size, void* d_ws, size_t ws_size,
                              hipStream_t stream) {
    const float* x = (const float*)d_in[0];
    const float* w = (const float*)d_in[1];
    float* out     = (float*)d_out;
    dim3 grid(16 * NTILES);   // 2048 blocks
    conv1d_kernel<<<grid, 256, 0, stream>>>(x, w, out);
}

// Round 3
// 149.197 us; speedup vs baseline: 1.0028x; 1.0028x over previous
//
#include <hip/hip_runtime.h>
#include <hip/hip_bf16.h>

#define L_IN   32768
#define L_OUT  32766   // (32768 - 3) + 1
#define C_IN   32
#define C_OUT  32
#define KW     3
// 16-wide l-tiles: 2048 tiles per batch image; 8 tiles per wave ->
// 256 waves per batch, 4096 waves total, 1024 blocks of 256 threads.

typedef __attribute__((ext_vector_type(8))) short  short8;   // 8 bf16 = 4 VGPRs (A/B frag)
typedef __attribute__((ext_vector_type(4))) float  floatx4;  // C/D frag

__device__ __forceinline__ unsigned pack2_bf16(float a, float b) {
    __hip_bfloat162 h2 = __float22bfloat162_rn(make_float2(a, b));
    union { __hip_bfloat162 h; unsigned u; } c; c.h = h2; return c.u;
}

__device__ __forceinline__ short8 pack8_bf16(const float* f) {
    union { short8 s; unsigned u[4]; } r;
#pragma unroll
    for (int p = 0; p < 4; ++p) r.u[p] = pack2_bf16(f[2*p], f[2*p+1]);
    return r.s;
}

__global__ __launch_bounds__(256) void conv1d_mfma(
    const float* __restrict__ x, const float* __restrict__ w,
    float* __restrict__ out)
{
    const int tid  = threadIdx.x;
    const int lane = tid & 63;
    const int wid  = (blockIdx.x << 2) | (tid >> 6);   // global wave id, 0..4095
    const int m    = lane & 15;    // A row (l offset) / D col-index source
    const int kq   = lane >> 4;    // quad 0..3

    const int b      = wid >> 8;           // 256 waves per batch image
    const int l_base = (wid & 255) << 7;   // 8 consecutive 16-wide l-tiles

    // ---- B-frags: weights, loaded once per wave, held in VGPRs ----
    // B[k=ci][n=co] layout: n = lane&15 (co within co-tile), k = kq*8 + j
    short8 Bf[KW][2];
#pragma unroll
    for (int cot = 0; cot < 2; ++cot) {
        const float* wp = w + (size_t)(cot*16 + m) * (C_IN*KW);
#pragma unroll
        for (int kw = 0; kw < KW; ++kw) {
            float f[8];
#pragma unroll
            for (int j = 0; j < 8; ++j) f[j] = wp[(kq*8 + j)*KW + kw];
            Bf[kw][cot] = pack8_bf16(f);
        }
    }

    // x rows for this lane's k-slice: ci = kq*8 + j
    const float* xb = x + ((size_t)b * C_IN + (size_t)(kq*8)) * L_IN;

#pragma unroll 2
    for (int t = 0; t < 8; ++t) {
        const int l0 = l_base + t*16;

        // ---- A-frags: x patches. A[m'][k]: m'=lane&15 -> l=l0+m'+kw, k=kq*8+j -> ci
        short8 Af[KW];
#pragma unroll
        for (int kw = 0; kw < KW; ++kw) {
            int col = l0 + m + kw;
            col = (col < L_IN) ? col : (L_IN - 1);   // clamped cols only feed discarded rows
            float f[8];
#pragma unroll
            for (int j = 0; j < 8; ++j) f[j] = xb[(size_t)j * L_IN + col];
            Af[kw] = pack8_bf16(f);
        }

        floatx4 acc0 = {0.f, 0.f, 0.f, 0.f};
        floatx4 acc1 = {0.f, 0.f, 0.f, 0.f};
#pragma unroll
        for (int kw = 0; kw < KW; ++kw) {
            acc0 = __builtin_amdgcn_mfma_f32_16x16x32_bf16(Af[kw], Bf[kw][0], acc0, 0, 0, 0);
            acc1 = __builtin_amdgcn_mfma_f32_16x16x32_bf16(Af[kw], Bf[kw][1], acc1, 0, 0, 0);
        }

        // ---- store: D col=lane&15 -> co, row=kq*4+r -> l (4 consecutive l per lane)
        const int ls = l0 + kq*4;                    // ls <= 32764 always (even)
#pragma unroll
        for (int cot = 0; cot < 2; ++cot) {
            const floatx4 a = cot ? acc1 : acc0;
            float* orow = out + ((size_t)b * C_OUT + (cot*16 + m)) * L_OUT;
            // row base byte offset = k*131064 (mult of 8) + ls*4 (even*4) -> 8B aligned
            *(float2*)(orow + ls) = make_float2(a[0], a[1]);       // always in-bounds
            if (ls + 2 < L_OUT)                                    // false only at l=32766
                *(float2*)(orow + ls + 2) = make_float2(a[2], a[3]);
        }
    }
}

extern "C" void kernel_launch(void* const* d_in, const int* in_sizes, int n_in,
                              void* d_out, int out_size, void* d_ws, size_t ws_size,
                              hipStream_t stream) {
    const float* x = (const float*)d_in[0];
    const float* w = (const float*)d_in[1];
    float* out     = (float*)d_out;
    conv1d_mfma<<<dim3(1024), 256, 0, stream>>>(x, w, out);
}